// Round 8
// baseline (207.532 us; speedup 1.0000x reference)
//
#include <hip/hip_runtime.h>
#include <math.h>

// Problem constants (match reference)
constexpr int   B       = 2048;
constexpr int   P       = 4;
constexpr int   D       = 256;       // K of the GEMM
constexpr int   NNEG    = 32768;
constexpr int   NTILES  = NNEG / 64; // per-row exp2-sum partials (64-col patches)
constexpr float TEMP    = 0.05f;
constexpr float ALPHA   = 0.1f;
constexpr float EPS     = 1e-12f;
constexpr float INV_T   = 1.0f / TEMP;
// A-side rows are pre-scaled by (1/T)*log2(e) so the MFMA accumulator is
// directly q = sim/T * log2(e), and exp(sim/T) = exp2(q).  |q| <= ~30 so no
// max-tracking is needed, and 28.85 << 448 (fp8 e4m3 max) so the scale is
// fp8-safe; fp relative precision is scale-invariant.
constexpr float SCALE_Q = 28.853900817779268f;

typedef float f32x4 __attribute__((ext_vector_type(4)));
typedef int   i32x8 __attribute__((ext_vector_type(8)));

// fp32 -> bf16 (RNE), bit-level
__device__ inline unsigned short f2bf(float f) {
  unsigned int u = __float_as_uint(f);
  u = (u + 0x7fffu + ((u >> 16) & 1u)) >> 16;
  return (unsigned short)u;
}
// bf16 bits -> fp32
__device__ inline float bf2f(unsigned short u) {
  return __uint_as_float((unsigned int)u << 16);
}

// Full 16-lane-row sum via 4 ROW_ROR DPP steps (VALU pipe only, no LDS).
// DPP ctrl must be a LITERAL constant: 0x121=ror1, 0x122=ror2, 0x124=ror4,
// 0x128=ror8.  (Verified working in rounds 5-7.)
__device__ inline float ror16_add(float v) {
  int x;
  x = __builtin_amdgcn_update_dpp(0, __float_as_int(v), 0x121, 0xf, 0xf, true);
  v += __int_as_float(x);
  x = __builtin_amdgcn_update_dpp(0, __float_as_int(v), 0x122, 0xf, 0xf, true);
  v += __int_as_float(x);
  x = __builtin_amdgcn_update_dpp(0, __float_as_int(v), 0x124, 0xf, 0xf, true);
  v += __int_as_float(x);
  x = __builtin_amdgcn_update_dpp(0, __float_as_int(v), 0x128, 0xf, 0xf, true);
  v += __int_as_float(x);
  return v;
}

// ---------------------------------------------------------------------------
// FP8 LANE-MAJOR layout: element (row, k) of a [R x 256] fp8 matrix is at
// BYTE index  p*4096 + h*2048 + t*512 + r*32 + b
// where p=row>>4 (16-row panel, 4096 B contiguous), r=row&15, h=k>>7
// (K=128 half), t=(k>>5)&3 (lane k-group), b=k&31.
// MFMA 16x16x128 lane l = r + 16t reads its 32 operand bytes CONTIGUOUSLY at
// half_base + l*32 (since t*512 + r*32 == l*32).  A and B use the identical
// (row,k)->byte bijection, so the MFMA pairs A/B k-positions consistently and
// the dot product is exact for any internal HW byte->k mapping (verified
// absmax 0.0 in rounds 3, 5, 6, 7).
// ---------------------------------------------------------------------------

// ---------------------------------------------------------------------------
// Kernel 1 (fused prep).  UNCHANGED except: each thread also zeroes one
// part_s slot (the workspace arrives POISONED from the harness fill, and the
// negsim epilogue now accumulates into part_s with atomicAdd).
// Grid 4224 x 256 = 1,081,344 threads >= B*NTILES = 1,048,576 slots.
// ---------------------------------------------------------------------------
constexpr int NPANEL = (B + NNEG) / 16;      // 2176
constexpr int LSTR   = 264;                  // LDS row stride in ushorts

__global__ __launch_bounds__(256) void prep_kernel(
    const float* __restrict__ a,
    const float* __restrict__ pzx,
    const float* __restrict__ n,
    unsigned char* __restrict__ a_f8,
    unsigned char* __restrict__ n_f8,
    float* __restrict__ pos_sim,
    float* __restrict__ part_s,
    float* __restrict__ loss_acc,
    unsigned int* __restrict__ ticket) {
  if (blockIdx.x == 0 && threadIdx.x == 0) { *loss_acc = 0.0f; *ticket = 0u; }
  {  // zero part_s (poisoned workspace; negsim accumulates atomically)
    int gidx = blockIdx.x * 256 + threadIdx.x;
    if (gidx < B * NTILES) part_s[gidx] = 0.0f;
  }
  const int id   = blockIdx.x;
  const int tid  = threadIdx.x;
  const int wave = tid >> 6;
  const int lane = tid & 63;

  if (id < NPANEL) {
    __shared__ __align__(16) unsigned short sm[16 * LSTR];
    const float* src; unsigned char* dst; int prow; float post;
    if (id < B / 16) { src = a; dst = a_f8; prow = id;          post = SCALE_Q; }
    else             { src = n; dst = n_f8; prow = id - B / 16; post = 1.0f; }

    // Phase 1: normalize rows into LDS (bf16).
#pragma unroll
    for (int rr = 0; rr < 4; rr++) {
      const int r = wave * 4 + rr;                       // 0..15
      float4 v = ((const float4*)(src + ((size_t)prow * 16 + r) * D))[lane];
      float ss = v.x * v.x + v.y * v.y + v.z * v.z + v.w * v.w;
#pragma unroll
      for (int off = 32; off > 0; off >>= 1) ss += __shfl_xor(ss, off, 64);
      float inv = post / fmaxf(sqrtf(ss), EPS);
      ushort4 o;
      o.x = f2bf(v.x * inv); o.y = f2bf(v.y * inv);
      o.z = f2bf(v.z * inv); o.w = f2bf(v.w * inv);
      *(ushort4*)&sm[r * LSTR + lane * 4] = o;
    }
    __syncthreads();

    // Phase 2: thread t emits fp8 panel bytes [t*16,+16) as one uint4 store.
    // Byte o: h=o>>11, t2=(o>>9)&3, r=(o>>5)&15, b=o&31; k = h*128+t2*32+b.
    // For o = tid*16: one row r, 16 consecutive k starting at k0.
    const int o  = tid * 16;
    const int r  = (o >> 5) & 15;
    const int k0 = (o >> 11) * 128 + ((o >> 9) & 3) * 32 + (o & 31);
    const unsigned short* s1 = &sm[r * LSTR + k0];   // 16 consecutive bf16
    uint4 ov;
    {
      int w0 = __builtin_amdgcn_cvt_pk_fp8_f32(bf2f(s1[0]),  bf2f(s1[1]),  0,  false);
      w0     = __builtin_amdgcn_cvt_pk_fp8_f32(bf2f(s1[2]),  bf2f(s1[3]),  w0, true);
      int w1 = __builtin_amdgcn_cvt_pk_fp8_f32(bf2f(s1[4]),  bf2f(s1[5]),  0,  false);
      w1     = __builtin_amdgcn_cvt_pk_fp8_f32(bf2f(s1[6]),  bf2f(s1[7]),  w1, true);
      int w2 = __builtin_amdgcn_cvt_pk_fp8_f32(bf2f(s1[8]),  bf2f(s1[9]),  0,  false);
      w2     = __builtin_amdgcn_cvt_pk_fp8_f32(bf2f(s1[10]), bf2f(s1[11]), w2, true);
      int w3 = __builtin_amdgcn_cvt_pk_fp8_f32(bf2f(s1[12]), bf2f(s1[13]), 0,  false);
      w3     = __builtin_amdgcn_cvt_pk_fp8_f32(bf2f(s1[14]), bf2f(s1[15]), w3, true);
      ov.x = (unsigned)w0; ov.y = (unsigned)w1;
      ov.z = (unsigned)w2; ov.w = (unsigned)w3;
    }
    *(uint4*)(dst + (size_t)prow * 4096 + tid * 16) = ov;
  } else {
    int pw = (id - NPANEL) * 4 + wave;   // 0..B*P-1
    if (pw >= B * P) return;
    int b = pw >> 2;                     // P == 4
    float4 av = ((const float4*)(a + (size_t)b * D))[lane];
    float4 pv = ((const float4*)(pzx + (size_t)pw * D))[lane];
    float d  = av.x * pv.x + av.y * pv.y + av.z * pv.z + av.w * pv.w;
    float sa = av.x * av.x + av.y * av.y + av.z * av.z + av.w * av.w;
    float sp = pv.x * pv.x + pv.y * pv.y + pv.z * pv.z + pv.w * pv.w;
#pragma unroll
    for (int off = 32; off > 0; off >>= 1) {
      d  += __shfl_xor(d, off, 64);
      sa += __shfl_xor(sa, off, 64);
      sp += __shfl_xor(sp, off, 64);
    }
    if (lane == 0) {
      float inva = 1.0f / fmaxf(sqrtf(sa), EPS);
      float invp = 1.0f / fmaxf(sqrtf(sp), EPS);
      pos_sim[pw] = d * inva * invp * INV_T;
    }
  }
}

// ---------------------------------------------------------------------------
// Kernel 2: MX-scaled fp8 MFMA GEMM, PERSISTENT and now BARRIER-FREE in the
// K-loop.  Round-7 post-mortem: registers clean but negsim ~31.5us = 4x the
// 7.4us floor; the 2 barriers/iteration drained MFMA+VMEM pipes 16x and
// synchronized all 8 waves' B-load bursts.  This version removes part_l and
// both in-loop barriers entirely:
//  * epilogue pair-combine -> 2 atomicAdd per part_s slot (IEEE a+b == b+a
//    bitwise, so still deterministic/exact; part_s zeroed in prep).
//  * every wave free-runs its 8 iterations; each B load issues >= 8 MFMAs
//    (~280 cyc) + one epilogue before its use -> L2 latency hidden without
//    wave synchronization.
// Geometry unchanged from r7: 512 blocks x 512 threads, block = mblk x
// ngroup, wave tile 64x32 (acc=32 regs), disjoint B panels per wave
// (256 MB L2 B traffic, ~7.4us floor = MFMA floor), A staged to LDS once,
// h-granular copy-free bfA/bfB ping-pong, #pragma unroll 1 on the it-loop.
// ---------------------------------------------------------------------------
__global__ __launch_bounds__(512, 4) void negsim_mfma_kernel(
    const unsigned char* __restrict__ Af,   // fp8 lane-major [B][256]
    const unsigned char* __restrict__ Nf,   // fp8 lane-major [NNEG][256]
    float* __restrict__ part_s) {           // [B][NTILES], pre-zeroed
  __shared__ __align__(16) unsigned char As[4 * 4096];  // 16 KB (4 panels)

  const int tid  = threadIdx.x;
  const int wave = tid >> 6;   // 0..7 : 32-col patch within the 256-col strip
  const int lane = tid & 63;

  const int id     = blockIdx.x;     // 0..511
  const int ngroup = id & 15;        // 0..15 : 2048-col super-strip (XCD-local)
  const int mblk   = id >> 4;        // 0..31
  const int m0     = mblk * 64;

  // ---- stage A-tile once (16 KB, linear in global AND LDS):
  //      8 waves x 2 instr, each 1 KB. ----
#pragma unroll
  for (int t = 0; t < 2; t++) {
    const int s = wave * 2 + t;
    __builtin_amdgcn_global_load_lds(
        (const __attribute__((address_space(1))) unsigned int*)
            (Af + (size_t)(m0 >> 4) * 4096 + s * 1024 + lane * 16),
        (__attribute__((address_space(3))) unsigned int*)(As + s * 1024 + lane * 16),
        16, 0, 0);
  }

  // Panel base for this wave at iteration it: pn(it) = ngroup*128 + it*16 +
  // wave*2 (each wave owns panels pn, pn+1 = 32 cols; disjoint across waves).
  const unsigned char* Bw = Nf + (size_t)(ngroup * 128 + wave * 2) * 4096 + lane * 32;

  // Prologue: bfA <- (it=0, h=0).
  i32x8 bfA0 = *(const i32x8*)(Bw);
  i32x8 bfA1 = *(const i32x8*)(Bw + 4096);

  __syncthreads();   // drains the A staging (the kernel's ONLY barrier)

  const int colbase = ngroup * 32 + (wave >> 1);   // + it*4
  const int rowbase = m0 + (lane >> 4) * 4;        // + mi*16 + rr

#pragma unroll 1
  for (int it = 0; it < 8; it++) {
    const unsigned char* Bp  = Bw + (size_t)it * 16 * 4096;
    const unsigned char* Bpn = Bw + (size_t)(((it + 1) & 7) * 16) * 4096;

    f32x4 acc[4][2] = {};

    // ---- phase h=0: issue bfB <- (it, h=1); compute with bfA ----
    i32x8 bfB0 = *(const i32x8*)(Bp + 2048);
    i32x8 bfB1 = *(const i32x8*)(Bp + 4096 + 2048);
#pragma unroll
    for (int mi = 0; mi < 4; mi++) {
      i32x8 af = *(const i32x8*)&As[mi * 4096 + lane * 32];
      acc[mi][0] = __builtin_amdgcn_mfma_scale_f32_16x16x128_f8f6f4(
          af, bfA0, acc[mi][0], 0, 0, 0, 0x7f7f7f7f, 0, 0x7f7f7f7f);
      acc[mi][1] = __builtin_amdgcn_mfma_scale_f32_16x16x128_f8f6f4(
          af, bfA1, acc[mi][1], 0, 0, 0, 0x7f7f7f7f, 0, 0x7f7f7f7f);
    }

    // ---- phase h=1: issue bfA <- (it+1, h=0) (wraps on last it; redundant
    //      but valid load); compute with bfB ----
    bfA0 = *(const i32x8*)(Bpn);
    bfA1 = *(const i32x8*)(Bpn + 4096);
#pragma unroll
    for (int mi = 0; mi < 4; mi++) {
      i32x8 af = *(const i32x8*)&As[mi * 4096 + 2048 + lane * 32];
      acc[mi][0] = __builtin_amdgcn_mfma_scale_f32_16x16x128_f8f6f4(
          af, bfB0, acc[mi][0], 0, 0, 0, 0x7f7f7f7f, 0, 0x7f7f7f7f);
      acc[mi][1] = __builtin_amdgcn_mfma_scale_f32_16x16x128_f8f6f4(
          af, bfB1, acc[mi][1], 0, 0, 0, 0x7f7f7f7f, 0, 0x7f7f7f7f);
    }

    // ---- Epilogue (no barrier).  C/D layout row = mi*16 + (lane>>4)*4 +
    //      rr, col = ni*16+(lane&15) (shape-determined; verified).  32-col
    //      partial = 2 exp2 adds + ror16; the two waves sharing a 64-col
    //      slot combine via atomicAdd (exactly 2 adds/slot: order-invariant
    //      bitwise, part_s pre-zeroed in prep). ----
    const int col = colbase + it * 4;
#pragma unroll
    for (int mi = 0; mi < 4; mi++) {
#pragma unroll
      for (int rr = 0; rr < 4; rr++) {
        float e = __builtin_amdgcn_exp2f(acc[mi][0][rr]) +
                  __builtin_amdgcn_exp2f(acc[mi][1][rr]);
        e = ror16_add(e);
        if ((lane & 15) == 0)
          atomicAdd(&part_s[(size_t)(rowbase + mi * 16 + rr) * NTILES + col], e);
      }
    }
  }
}

// ---------------------------------------------------------------------------
// Kernel 3: per-anchor loss + final reduce — UNCHANGED from the verified
// version (NTILES=512 layout).
// ---------------------------------------------------------------------------
__global__ void loss_kernel(const float* __restrict__ part_s,
                            const float* __restrict__ pos_sim,
                            const int* __restrict__ counts,
                            float* __restrict__ loss_acc,
                            unsigned int* __restrict__ ticket,
                            float* __restrict__ out) {
  const int tid = threadIdx.x;
  const int b   = blockIdx.x * 16 + (tid >> 4);
  const int sub = tid & 15;
  const float* ps = part_s + (size_t)b * NTILES;
  float s = 0.0f;
#pragma unroll
  for (int i = 0; i < NTILES / 16; i++) s += ps[sub + i * 16];
  s += __shfl_xor(s, 1, 64);
  s += __shfl_xor(s, 2, 64);
  s += __shfl_xor(s, 4, 64);
  s += __shfl_xor(s, 8, 64);   // 16-lane group now holds full S

  float acc = 0.0f;
  if (sub == 0) {
    float L = logf(s);  // neg_lse in natural-log units
    float p0 = pos_sim[b * P + 0], p1 = pos_sim[b * P + 1];
    float p2 = pos_sim[b * P + 2], p3 = pos_sim[b * P + 3];
    int cnt = counts[b];
    float pj[P] = {p0, p1, p2, p3};
#pragma unroll
    for (int jj = 0; jj < P; jj++) {
      if (jj < cnt) {
        float hi = fmaxf(pj[jj], L), lo = fminf(pj[jj], L);
        acc += hi + log1pf(__expf(lo - hi)) - pj[jj];
      }
    }
    float mp = fmaxf(fmaxf(p0, p1), fmaxf(p2, p3));
    float e0 = __expf(p0 - mp), e1 = __expf(p1 - mp);
    float e2 = __expf(p2 - mp), e3 = __expf(p3 - mp);
    float se = e0 + e1 + e2 + e3;
    float wps = (e0 * p0 + e1 * p1 + e2 * p2 + e3 * p3) / se;
    if (cnt > 1) {
      float hi = fmaxf(wps, L), lo = fminf(wps, L);
      acc += ALPHA * (hi + log1pf(__expf(lo - hi)) - wps);
    }
  }
#pragma unroll
  for (int off = 32; off > 0; off >>= 1) acc += __shfl_xor(acc, off, 64);
  __shared__ float sa[4];
  int wid = tid >> 6, lane = tid & 63;
  if (lane == 0) sa[wid] = acc;
  __syncthreads();
  if (tid == 0) {
    atomicAdd(loss_acc, sa[0] + sa[1] + sa[2] + sa[3]);
    __threadfence();
    unsigned int t = atomicAdd(ticket, 1u);
    if (t == (unsigned int)gridDim.x - 1u) {
      float total = atomicAdd(loss_acc, 0.0f);  // atomic read-back
      out[0] = total / (float)B;
    }
  }
}

// ---------------------------------------------------------------------------
extern "C" void kernel_launch(void* const* d_in, const int* in_sizes, int n_in,
                              void* d_out, int out_size, void* d_ws,
                              size_t ws_size, hipStream_t stream) {
  const float* anc    = (const float*)d_in[0];
  const float* pos    = (const float*)d_in[1];
  const float* neg    = (const float*)d_in[2];
  const int*   counts = (const int*)d_in[3];
  float* out = (float*)d_out;

  // Workspace layout: ~12.6 MB (identical to the verified 126us kernel)
  unsigned char* a_f8 = (unsigned char*)d_ws;            // B*D      (0.5 MB)
  unsigned char* n_f8 = a_f8 + (size_t)B * D;            // NNEG*D   (8 MB)
  float* part_s  = (float*)(n_f8 + (size_t)NNEG * D);    // B*NTILES (4 MB)
  float* pos_sim = part_s + (size_t)B * NTILES;          // B*P
  float* loss_acc = pos_sim + B * P;                     // 1
  unsigned int* ticket = (unsigned int*)(loss_acc + 1);  // 1

  // 2176 panel blocks + 2048 possim blocks
  prep_kernel<<<NPANEL + B * P / 4, 256, 0, stream>>>(
      anc, pos, neg, a_f8, n_f8, pos_sim, part_s, loss_acc, ticket);

  negsim_mfma_kernel<<<512, 512, 0, stream>>>(a_f8, n_f8, part_s);

  loss_kernel<<<B / 16, 256, 0, stream>>>(part_s, pos_sim, counts,
                                          loss_acc, ticket, out);
}

// Round 9
// 118.039 us; speedup vs baseline: 1.7582x; 1.7582x over previous
//
#include <hip/hip_runtime.h>
#include <math.h>

// Problem constants (match reference)
constexpr int   B       = 2048;
constexpr int   P       = 4;
constexpr int   D       = 256;       // K of the GEMM
constexpr int   NNEG    = 32768;
constexpr int   NTILES  = NNEG / 64; // per-row exp2-sum partials (64-col patches)
constexpr float TEMP    = 0.05f;
constexpr float ALPHA   = 0.1f;
constexpr float EPS     = 1e-12f;
constexpr float INV_T   = 1.0f / TEMP;
// A-side rows are pre-scaled by (1/T)*log2(e) so the MFMA accumulator is
// directly q = sim/T * log2(e), and exp(sim/T) = exp2(q).  |q| <= ~30 so no
// max-tracking is needed, and 28.85 << 448 (fp8 e4m3 max) so the scale is
// fp8-safe; fp relative precision is scale-invariant.
constexpr float SCALE_Q = 28.853900817779268f;

typedef float f32x4 __attribute__((ext_vector_type(4)));
typedef int   i32x8 __attribute__((ext_vector_type(8)));

// fp32 -> bf16 (RNE), bit-level
__device__ inline unsigned short f2bf(float f) {
  unsigned int u = __float_as_uint(f);
  u = (u + 0x7fffu + ((u >> 16) & 1u)) >> 16;
  return (unsigned short)u;
}
// bf16 bits -> fp32
__device__ inline float bf2f(unsigned short u) {
  return __uint_as_float((unsigned int)u << 16);
}

// Full 16-lane-row sum via 4 ROW_ROR DPP steps (VALU pipe only, no LDS).
// DPP ctrl must be a LITERAL constant: 0x121=ror1, 0x122=ror2, 0x124=ror4,
// 0x128=ror8.  (Verified working in rounds 5-8.)
__device__ inline float ror16_add(float v) {
  int x;
  x = __builtin_amdgcn_update_dpp(0, __float_as_int(v), 0x121, 0xf, 0xf, true);
  v += __int_as_float(x);
  x = __builtin_amdgcn_update_dpp(0, __float_as_int(v), 0x122, 0xf, 0xf, true);
  v += __int_as_float(x);
  x = __builtin_amdgcn_update_dpp(0, __float_as_int(v), 0x124, 0xf, 0xf, true);
  v += __int_as_float(x);
  x = __builtin_amdgcn_update_dpp(0, __float_as_int(v), 0x128, 0xf, 0xf, true);
  v += __int_as_float(x);
  return v;
}

// ---------------------------------------------------------------------------
// FP8 layouts.  Operand bijection (BOTH matrices, unchanged, verified absmax
// 0.0 rounds 3-8): lane l = r + 16t holds operand byte j = k-offset within
// its 32-k span; k = h*128 + t*32 + j, row = panel*16 + r.
//
// N (B-operand, read global->VGPR, no banks): LANE-MAJOR
//   byte = p*4096 + h*2048 + l*32 + j          (l*32 = t*512 + r*32)
//
// A (staged to LDS, read via ds_read_b128): CHUNK-SPLIT (NEW, round 9) —
//   the two 16-B halves (c = j>>4) of each lane's operand live 1024 B apart:
//   byte = p*4096 + h*2048 + c*1024 + l*16 + (j&15)
//   -> af read = TWO b128 at stride lane*16 (conflict-free; the old lane*32
//   single-span read was a 16-way bank conflict = SQ_LDS_BANK_CONFLICT 262K,
//   ~29us of LDS serialization — the real cap on rounds 5-8).
//   Byte j of the operand still maps to k = h*128+t*32+j (c*16 + (j&15) = j),
//   so the A/B pairing — and exactness — is unchanged.
// ---------------------------------------------------------------------------

// ---------------------------------------------------------------------------
// Kernel 1 (fused prep).  Phase 2 decode now differs per matrix (A chunk-
// split vs N lane-major); both remain "one row, 16 consecutive k" -> the
// LDS gather and cvt_pk chain are unchanged.
// ---------------------------------------------------------------------------
constexpr int NPANEL = (B + NNEG) / 16;      // 2176
constexpr int LSTR   = 264;                  // LDS row stride in ushorts

__global__ __launch_bounds__(256) void prep_kernel(
    const float* __restrict__ a,
    const float* __restrict__ pzx,
    const float* __restrict__ n,
    unsigned char* __restrict__ a_f8,
    unsigned char* __restrict__ n_f8,
    float* __restrict__ pos_sim,
    float* __restrict__ loss_acc,
    unsigned int* __restrict__ ticket) {
  if (blockIdx.x == 0 && threadIdx.x == 0) { *loss_acc = 0.0f; *ticket = 0u; }
  const int id   = blockIdx.x;
  const int tid  = threadIdx.x;
  const int wave = tid >> 6;
  const int lane = tid & 63;

  if (id < NPANEL) {
    __shared__ __align__(16) unsigned short sm[16 * LSTR];
    const bool isA = (id < B / 16);
    const float* src; unsigned char* dst; int prow; float post;
    if (isA) { src = a; dst = a_f8; prow = id;          post = SCALE_Q; }
    else     { src = n; dst = n_f8; prow = id - B / 16; post = 1.0f; }

    // Phase 1: normalize rows into LDS (bf16).
#pragma unroll
    for (int rr = 0; rr < 4; rr++) {
      const int r = wave * 4 + rr;                       // 0..15
      float4 v = ((const float4*)(src + ((size_t)prow * 16 + r) * D))[lane];
      float ss = v.x * v.x + v.y * v.y + v.z * v.z + v.w * v.w;
#pragma unroll
      for (int off = 32; off > 0; off >>= 1) ss += __shfl_xor(ss, off, 64);
      float inv = post / fmaxf(sqrtf(ss), EPS);
      ushort4 o;
      o.x = f2bf(v.x * inv); o.y = f2bf(v.y * inv);
      o.z = f2bf(v.z * inv); o.w = f2bf(v.w * inv);
      *(ushort4*)&sm[r * LSTR + lane * 4] = o;
    }
    __syncthreads();

    // Phase 2: thread t emits fp8 panel bytes [t*16,+16) as one uint4 store.
    // A (chunk-split): o = h<11> c<10> t<9:8> r<7:4> b'<3:0>
    //                  k0 = h*128 + t*32 + c*16, row r
    // N (lane-major):  o = h<11> t<10:9> r<8:5> b<4:0>
    //                  k0 = h*128 + t*32 + (o&16), row r
    const int o = tid * 16;
    int r, k0;
    if (isA) {
      r  = (o >> 4) & 15;
      k0 = (o >> 11) * 128 + ((o >> 8) & 3) * 32 + ((o >> 10) & 1) * 16;
    } else {
      r  = (o >> 5) & 15;
      k0 = (o >> 11) * 128 + ((o >> 9) & 3) * 32 + (o & 16);
    }
    const unsigned short* s1 = &sm[r * LSTR + k0];   // 16 consecutive bf16
    uint4 ov;
    {
      int w0 = __builtin_amdgcn_cvt_pk_fp8_f32(bf2f(s1[0]),  bf2f(s1[1]),  0,  false);
      w0     = __builtin_amdgcn_cvt_pk_fp8_f32(bf2f(s1[2]),  bf2f(s1[3]),  w0, true);
      int w1 = __builtin_amdgcn_cvt_pk_fp8_f32(bf2f(s1[4]),  bf2f(s1[5]),  0,  false);
      w1     = __builtin_amdgcn_cvt_pk_fp8_f32(bf2f(s1[6]),  bf2f(s1[7]),  w1, true);
      int w2 = __builtin_amdgcn_cvt_pk_fp8_f32(bf2f(s1[8]),  bf2f(s1[9]),  0,  false);
      w2     = __builtin_amdgcn_cvt_pk_fp8_f32(bf2f(s1[10]), bf2f(s1[11]), w2, true);
      int w3 = __builtin_amdgcn_cvt_pk_fp8_f32(bf2f(s1[12]), bf2f(s1[13]), 0,  false);
      w3     = __builtin_amdgcn_cvt_pk_fp8_f32(bf2f(s1[14]), bf2f(s1[15]), w3, true);
      ov.x = (unsigned)w0; ov.y = (unsigned)w1;
      ov.z = (unsigned)w2; ov.w = (unsigned)w3;
    }
    *(uint4*)(dst + (size_t)prow * 4096 + tid * 16) = ov;
  } else {
    int pw = (id - NPANEL) * 4 + wave;   // 0..B*P-1
    if (pw >= B * P) return;
    int b = pw >> 2;                     // P == 4
    float4 av = ((const float4*)(a + (size_t)b * D))[lane];
    float4 pv = ((const float4*)(pzx + (size_t)pw * D))[lane];
    float d  = av.x * pv.x + av.y * pv.y + av.z * pv.z + av.w * pv.w;
    float sa = av.x * av.x + av.y * av.y + av.z * av.z + av.w * av.w;
    float sp = pv.x * pv.x + pv.y * pv.y + pv.z * pv.z + pv.w * pv.w;
#pragma unroll
    for (int off = 32; off > 0; off >>= 1) {
      d  += __shfl_xor(d, off, 64);
      sa += __shfl_xor(sa, off, 64);
      sp += __shfl_xor(sp, off, 64);
    }
    if (lane == 0) {
      float inva = 1.0f / fmaxf(sqrtf(sa), EPS);
      float invp = 1.0f / fmaxf(sqrtf(sp), EPS);
      pos_sim[pw] = d * inva * invp * INV_T;
    }
  }
}

// ---------------------------------------------------------------------------
// Kernel 2: MX-scaled fp8 MFMA GEMM.  Structure = round 7 verbatim (the best
// verified version: persistent 512x512, wave tile 64x32, LDS pair-combine,
// 2 barriers/it, bfA/bfB ping-pong, unroll 1) with ONE change: af reads are
// now TWO conflict-free ds_read_b128 at lane*16 (chunk-split A layout)
// instead of one 16-way-conflicted lane*32 span.  Round-8 PMC showed the
// conflicts (262K) were ~29us of LDS serialization — the actual cap.
// (Atomics from round 8 reverted: 2 atomicAdd/slot cost 112us, WRITE 72MB.)
// ---------------------------------------------------------------------------
__global__ __launch_bounds__(512, 4) void negsim_mfma_kernel(
    const unsigned char* __restrict__ Af,   // fp8 chunk-split [B][256]
    const unsigned char* __restrict__ Nf,   // fp8 lane-major [NNEG][256]
    float* __restrict__ part_s) {           // [B][NTILES]
  __shared__ __align__(16) unsigned char As[4 * 4096];  // 16 KB (4 panels)
  __shared__ float part_l[8][64];                       // 2 KB combine buffer

  const int tid  = threadIdx.x;
  const int wave = tid >> 6;   // 0..7 : 32-col patch within the 256-col strip
  const int lane = tid & 63;

  const int id     = blockIdx.x;     // 0..511
  const int ngroup = id & 15;        // 0..15 : 2048-col super-strip (XCD-local)
  const int mblk   = id >> 4;        // 0..31
  const int m0     = mblk * 64;

  // ---- stage A-tile once (16 KB, linear in global AND LDS):
  //      8 waves x 2 instr, each 1 KB. ----
#pragma unroll
  for (int t = 0; t < 2; t++) {
    const int s = wave * 2 + t;
    __builtin_amdgcn_global_load_lds(
        (const __attribute__((address_space(1))) unsigned int*)
            (Af + (size_t)(m0 >> 4) * 4096 + s * 1024 + lane * 16),
        (__attribute__((address_space(3))) unsigned int*)(As + s * 1024 + lane * 16),
        16, 0, 0);
  }

  // Panel base for this wave at iteration it: pn(it) = ngroup*128 + it*16 +
  // wave*2 (each wave owns panels pn, pn+1 = 32 cols; disjoint across waves).
  const unsigned char* Bw = Nf + (size_t)(ngroup * 128 + wave * 2) * 4096 + lane * 32;

  // Prologue: bfA <- (it=0, h=0).
  i32x8 bfA0 = *(const i32x8*)(Bw);
  i32x8 bfA1 = *(const i32x8*)(Bw + 4096);

  __syncthreads();   // drains the A staging

  const int aoff = lane * 16;   // chunk-split af base offset (conflict-free)

#pragma unroll 1
  for (int it = 0; it < 8; it++) {
    const unsigned char* Bp  = Bw + (size_t)it * 16 * 4096;
    const unsigned char* Bpn = Bw + (size_t)(((it + 1) & 7) * 16) * 4096;

    f32x4 acc[4][2] = {};

    // ---- phase h=0: issue bfB <- (it, h=1); compute with bfA ----
    i32x8 bfB0 = *(const i32x8*)(Bp + 2048);
    i32x8 bfB1 = *(const i32x8*)(Bp + 4096 + 2048);
#pragma unroll
    for (int mi = 0; mi < 4; mi++) {
      int4 lo = *(const int4*)&As[mi * 4096 + aoff];
      int4 hi = *(const int4*)&As[mi * 4096 + 1024 + aoff];
      i32x8 af;
      af[0] = lo.x; af[1] = lo.y; af[2] = lo.z; af[3] = lo.w;
      af[4] = hi.x; af[5] = hi.y; af[6] = hi.z; af[7] = hi.w;
      acc[mi][0] = __builtin_amdgcn_mfma_scale_f32_16x16x128_f8f6f4(
          af, bfA0, acc[mi][0], 0, 0, 0, 0x7f7f7f7f, 0, 0x7f7f7f7f);
      acc[mi][1] = __builtin_amdgcn_mfma_scale_f32_16x16x128_f8f6f4(
          af, bfA1, acc[mi][1], 0, 0, 0, 0x7f7f7f7f, 0, 0x7f7f7f7f);
    }

    // ---- phase h=1: issue bfA <- (it+1, h=0) (wraps on last it; redundant
    //      but valid load); compute with bfB ----
    bfA0 = *(const i32x8*)(Bpn);
    bfA1 = *(const i32x8*)(Bpn + 4096);
#pragma unroll
    for (int mi = 0; mi < 4; mi++) {
      int4 lo = *(const int4*)&As[mi * 4096 + 2048 + aoff];
      int4 hi = *(const int4*)&As[mi * 4096 + 2048 + 1024 + aoff];
      i32x8 af;
      af[0] = lo.x; af[1] = lo.y; af[2] = lo.z; af[3] = lo.w;
      af[4] = hi.x; af[5] = hi.y; af[6] = hi.z; af[7] = hi.w;
      acc[mi][0] = __builtin_amdgcn_mfma_scale_f32_16x16x128_f8f6f4(
          af, bfB0, acc[mi][0], 0, 0, 0, 0x7f7f7f7f, 0, 0x7f7f7f7f);
      acc[mi][1] = __builtin_amdgcn_mfma_scale_f32_16x16x128_f8f6f4(
          af, bfB1, acc[mi][1], 0, 0, 0, 0x7f7f7f7f, 0, 0x7f7f7f7f);
    }

    // ---- Epilogue.  C/D layout row = mi*16 + (lane>>4)*4 + rr,
    //      col = ni*16+(lane&15) (shape-determined on gfx950; verified).
    //      32-col partial = 2 exp2 adds + ror16; pair-combine to 64-col
    //      slots via 2 KB LDS (proven r3/r7 pattern). ----
#pragma unroll
    for (int mi = 0; mi < 4; mi++) {
#pragma unroll
      for (int rr = 0; rr < 4; rr++) {
        float e = __builtin_amdgcn_exp2f(acc[mi][0][rr]) +
                  __builtin_amdgcn_exp2f(acc[mi][1][rr]);
        e = ror16_add(e);
        if ((lane & 15) == 0)
          part_l[wave][mi * 16 + (lane >> 4) * 4 + rr] = e;
      }
    }
    __syncthreads();
    if (tid < 256) {
      const int u4  = tid >> 6;    // 0..3 : 64-col slot within the strip
      const int row = tid & 63;
      float s64 = part_l[2 * u4][row] + part_l[2 * u4 + 1][row];
      part_s[(size_t)(m0 + row) * NTILES + (ngroup * 32 + it * 4 + u4)] = s64;
    }
    __syncthreads();   // part_l free for next iteration
  }
}

// ---------------------------------------------------------------------------
// Kernel 3: per-anchor loss + final reduce — UNCHANGED from the verified
// version (NTILES=512 layout).
// ---------------------------------------------------------------------------
__global__ void loss_kernel(const float* __restrict__ part_s,
                            const float* __restrict__ pos_sim,
                            const int* __restrict__ counts,
                            float* __restrict__ loss_acc,
                            unsigned int* __restrict__ ticket,
                            float* __restrict__ out) {
  const int tid = threadIdx.x;
  const int b   = blockIdx.x * 16 + (tid >> 4);
  const int sub = tid & 15;
  const float* ps = part_s + (size_t)b * NTILES;
  float s = 0.0f;
#pragma unroll
  for (int i = 0; i < NTILES / 16; i++) s += ps[sub + i * 16];
  s += __shfl_xor(s, 1, 64);
  s += __shfl_xor(s, 2, 64);
  s += __shfl_xor(s, 4, 64);
  s += __shfl_xor(s, 8, 64);   // 16-lane group now holds full S

  float acc = 0.0f;
  if (sub == 0) {
    float L = logf(s);  // neg_lse in natural-log units
    float p0 = pos_sim[b * P + 0], p1 = pos_sim[b * P + 1];
    float p2 = pos_sim[b * P + 2], p3 = pos_sim[b * P + 3];
    int cnt = counts[b];
    float pj[P] = {p0, p1, p2, p3};
#pragma unroll
    for (int jj = 0; jj < P; jj++) {
      if (jj < cnt) {
        float hi = fmaxf(pj[jj], L), lo = fminf(pj[jj], L);
        acc += hi + log1pf(__expf(lo - hi)) - pj[jj];
      }
    }
    float mp = fmaxf(fmaxf(p0, p1), fmaxf(p2, p3));
    float e0 = __expf(p0 - mp), e1 = __expf(p1 - mp);
    float e2 = __expf(p2 - mp), e3 = __expf(p3 - mp);
    float se = e0 + e1 + e2 + e3;
    float wps = (e0 * p0 + e1 * p1 + e2 * p2 + e3 * p3) / se;
    if (cnt > 1) {
      float hi = fmaxf(wps, L), lo = fminf(wps, L);
      acc += ALPHA * (hi + log1pf(__expf(lo - hi)) - wps);
    }
  }
#pragma unroll
  for (int off = 32; off > 0; off >>= 1) acc += __shfl_xor(acc, off, 64);
  __shared__ float sa[4];
  int wid = tid >> 6, lane = tid & 63;
  if (lane == 0) sa[wid] = acc;
  __syncthreads();
  if (tid == 0) {
    atomicAdd(loss_acc, sa[0] + sa[1] + sa[2] + sa[3]);
    __threadfence();
    unsigned int t = atomicAdd(ticket, 1u);
    if (t == (unsigned int)gridDim.x - 1u) {
      float total = atomicAdd(loss_acc, 0.0f);  // atomic read-back
      out[0] = total / (float)B;
    }
  }
}

// ---------------------------------------------------------------------------
extern "C" void kernel_launch(void* const* d_in, const int* in_sizes, int n_in,
                              void* d_out, int out_size, void* d_ws,
                              size_t ws_size, hipStream_t stream) {
  const float* anc    = (const float*)d_in[0];
  const float* pos    = (const float*)d_in[1];
  const float* neg    = (const float*)d_in[2];
  const int*   counts = (const int*)d_in[3];
  float* out = (float*)d_out;

  // Workspace layout: ~12.6 MB (identical to the verified 126us kernel)
  unsigned char* a_f8 = (unsigned char*)d_ws;            // B*D      (0.5 MB)
  unsigned char* n_f8 = a_f8 + (size_t)B * D;            // NNEG*D   (8 MB)
  float* part_s  = (float*)(n_f8 + (size_t)NNEG * D);    // B*NTILES (4 MB)
  float* pos_sim = part_s + (size_t)B * NTILES;          // B*P
  float* loss_acc = pos_sim + B * P;                     // 1
  unsigned int* ticket = (unsigned int*)(loss_acc + 1);  // 1

  // 2176 panel blocks + 2048 possim blocks
  prep_kernel<<<NPANEL + B * P / 4, 256, 0, stream>>>(
      anc, pos, neg, a_f8, n_f8, pos_sim, loss_acc, ticket);

  negsim_mfma_kernel<<<512, 512, 0, stream>>>(a_f8, n_f8, part_s);

  loss_kernel<<<B / 16, 256, 0, stream>>>(part_s, pos_sim, counts,
                                          loss_acc, ticket, out);
}